// Round 3
// baseline (1382.583 us; speedup 1.0000x reference)
//
#include <hip/hip_runtime.h>
#include <math.h>

#define TOK 8192   // B*S tokens
#define HD  512    // hidden
#define NE  8      // experts
#define DFF 2048   // ffn dim

// ---------- bf16 helpers ----------
typedef __attribute__((ext_vector_type(8))) short bf16x8;
typedef __attribute__((ext_vector_type(4))) float floatx4;

__device__ inline unsigned short f2bf(float f) {
    union { float f; unsigned u; } v; v.f = f;
    unsigned r = v.u + 0x7FFFu + ((v.u >> 16) & 1u);   // round-nearest-even
    return (unsigned short)(r >> 16);
}

// ---------------- gating (fp32, exact) + fused x->bf16 conversion ----------------
__global__ __launch_bounds__(256) void gate_kernel(
    const float* __restrict__ x, const float* __restrict__ gW, const float* __restrict__ gb,
    int* __restrict__ seg_count, float* __restrict__ probs_sum,
    int* __restrict__ seg_token, float* __restrict__ seg_w,
    unsigned short* __restrict__ xb)
{
    __shared__ float sW[HD * NE];
    __shared__ float psum[NE];
    __shared__ int   lcount[NE];
    __shared__ int   lbase[NE];

    int tid = threadIdx.x;
    for (int i = tid; i < HD * NE; i += 256) sW[i] = gW[i];
    if (tid < NE) { psum[tid] = 0.f; lcount[tid] = 0; }
    __syncthreads();

    int t = blockIdx.x * 256 + tid;
    float logit[NE];
    #pragma unroll
    for (int e = 0; e < NE; e++) logit[e] = gb[e];

    const float4* xr4 = reinterpret_cast<const float4*>(x + (size_t)t * HD);
    ushort4* xbw = reinterpret_cast<ushort4*>(xb + (size_t)t * HD);
    for (int j4 = 0; j4 < HD / 4; j4++) {
        float4 xv = xr4[j4];
        int j = j4 * 4;
        ushort4 o; o.x = f2bf(xv.x); o.y = f2bf(xv.y); o.z = f2bf(xv.z); o.w = f2bf(xv.w);
        xbw[j4] = o;
        #pragma unroll
        for (int e = 0; e < NE; e++) {
            logit[e] += xv.x * sW[(j + 0) * NE + e] + xv.y * sW[(j + 1) * NE + e]
                      + xv.z * sW[(j + 2) * NE + e] + xv.w * sW[(j + 3) * NE + e];
        }
    }

    float mx = logit[0];
    #pragma unroll
    for (int e = 1; e < NE; e++) mx = fmaxf(mx, logit[e]);
    float pe[NE]; float s = 0.f;
    #pragma unroll
    for (int e = 0; e < NE; e++) { pe[e] = expf(logit[e] - mx); s += pe[e]; }
    float inv = 1.f / s;
    int l = tid & 63;
    #pragma unroll
    for (int e = 0; e < NE; e++) {          // wave-shuffle reduce, 1 LDS atomic per wave per e
        float v = pe[e] * inv;
        for (int off = 32; off; off >>= 1) v += __shfl_down(v, off);
        if (l == 0) atomicAdd(&psum[e], v);
    }

    // top-2, lowest-index tie break (matches jax.lax.top_k)
    int i0 = 0; float v0 = logit[0];
    #pragma unroll
    for (int e = 1; e < NE; e++) if (logit[e] > v0) { v0 = logit[e]; i0 = e; }
    int i1 = -1; float v1 = -3.4e38f;
    #pragma unroll
    for (int e = 0; e < NE; e++) if (e != i0 && logit[e] > v1) { v1 = logit[e]; i1 = e; }
    float e1 = expf(v1 - v0);
    float w0 = 1.f / (1.f + e1);
    float w1 = e1 / (1.f + e1);

    int r0 = atomicAdd(&lcount[i0], 1);
    int r1 = atomicAdd(&lcount[i1], 1);
    __syncthreads();
    if (tid < NE) lbase[tid] = atomicAdd(&seg_count[tid], lcount[tid]);
    __syncthreads();
    int p0 = lbase[i0] + r0;
    seg_token[i0 * TOK + p0] = t; seg_w[i0 * TOK + p0] = w0;
    int p1 = lbase[i1] + r1;
    seg_token[i1 * TOK + p1] = t; seg_w[i1 * TOK + p1] = w1;

    __syncthreads();
    if (tid < NE) atomicAdd(&probs_sum[tid], psum[tid]);
}

// ---------------- l_aux + counts ----------------
__global__ void finalize_kernel(const int* __restrict__ seg_count,
                                const float* __restrict__ probs_sum,
                                float* __restrict__ out_tail)
{
    int tid = threadIdx.x;
    __shared__ float p2[NE];
    if (tid < NE) {
        float p = probs_sum[tid] * (1.f / (float)TOK);
        p2[tid] = p * p;
        out_tail[1 + tid] = (float)seg_count[tid];
    }
    __syncthreads();
    if (tid == 0) {
        float ssum = 0.f;
        #pragma unroll
        for (int e = 0; e < NE; e++) ssum += p2[e];
        out_tail[0] = ssum * (float)NE;
    }
}

// ---------------- weight transpose: [E][R][C] fp32 -> [E][C][R] bf16 ----------------
__global__ __launch_bounds__(256) void transpose_bf16_kernel(const float* __restrict__ in,
                                                             unsigned short* __restrict__ out,
                                                             int R, int C)
{
    __shared__ float tile[64][65];
    int e = blockIdx.z;
    const float* src = in + (size_t)e * R * C;
    unsigned short* dst = out + (size_t)e * R * C;
    int c0 = blockIdx.x * 64, r0 = blockIdx.y * 64;
    int lc = threadIdx.x & 63, lrw = threadIdx.x >> 6;   // 4 row-groups
    #pragma unroll
    for (int rr = lrw; rr < 64; rr += 4)
        tile[rr][lc] = src[(size_t)(r0 + rr) * C + c0 + lc];
    __syncthreads();
    #pragma unroll
    for (int cc = lrw; cc < 64; cc += 4)
        dst[(size_t)(c0 + cc) * R + r0 + lc] = f2bf(tile[lc][cc]);
}

// ---------------- fused MFMA expert FFN ----------------
// Block = 32 tokens x one expert x one DFF z-slice. 4 waves.
// GEMM1 2x2 wave split (M-half x N-half); GEMM2 N-split (128 cols/wave).
#define BMT 32     // tokens per block
#define FK  64     // dff chunk
#define ZN  2      // DFF split factor
#define ZSLICE (DFF / ZN)
#define XS_LD 520  // xs leading dim (bf16): 1040 B -> 2-way bank alias (free)
#define HS_LD 72   // hs leading dim: 144 B -> 2-way bank alias (free)

__global__ __launch_bounds__(256, 4) void ffn_mfma_kernel(
    const unsigned short* __restrict__ xb,
    const unsigned short* __restrict__ W1t,   // [E][DFF][HD] bf16 (n-major)
    const float* __restrict__ b1,
    const unsigned short* __restrict__ W2t,   // [E][HD][DFF] bf16 (n-major)
    const float* __restrict__ b2,
    const int* __restrict__ seg_count, const int* __restrict__ seg_token,
    const float* __restrict__ seg_w, float* __restrict__ out)
{
    int e = blockIdx.z;
    int z = blockIdx.y;
    int cnt = seg_count[e];
    int n0 = blockIdx.x * BMT;
    if (n0 >= cnt) return;
    int rows = min(BMT, cnt - n0);

    __shared__ unsigned short xs[BMT * XS_LD];   // 33280 B
    __shared__ unsigned short hs[BMT * HS_LD];   //  4608 B
    __shared__ int   tok_s[BMT];
    __shared__ float wgt_s[BMT];

    int tid = threadIdx.x;
    if (tid < BMT) {
        int idx = (tid < rows) ? (n0 + tid) : n0;            // pad rows duplicate row 0
        tok_s[tid] = seg_token[e * TOK + idx];
        wgt_s[tid] = (tid < rows) ? seg_w[e * TOK + idx] : 0.f;
    }
    __syncthreads();

    // stage x rows (bf16): 8 threads per row, 128 B each
    {
        int r = tid >> 3, q = tid & 7;
        const uint4* src = (const uint4*)(xb + (size_t)tok_s[r] * HD) + q * 8;
        uint4* dst = (uint4*)&xs[(size_t)r * XS_LD + q * 64];
        #pragma unroll
        for (int i = 0; i < 8; i++) dst[i] = src[i];
    }
    __syncthreads();

    int w  = tid >> 6;          // wave id 0..3
    int l  = tid & 63;
    int lr = l & 15;
    int lk = (l >> 4) * 8;
    int crow = (l >> 4) * 4;
    int mh = w & 1;             // GEMM1 M-half
    int nh = w >> 1;            // GEMM1 N-half

    const unsigned short* w1e = W1t + ((size_t)e * DFF + (size_t)z * ZSLICE) * HD;
    const unsigned short* w2e = W2t + (size_t)e * HD * DFF + (size_t)z * ZSLICE;

    floatx4 acc2[2][8];         // 32 M x 128 N per wave
    #pragma unroll
    for (int i = 0; i < 2; i++)
        #pragma unroll
        for (int j = 0; j < 8; j++)
            acc2[i][j] = (floatx4){0.f, 0.f, 0.f, 0.f};

    for (int fc = 0; fc < ZSLICE; fc += FK) {
        // ---- GEMM1: h-chunk(32x64) = xs(32x512) @ W1slice[:, fc:fc+64]
        // wave(mh,nh): M rows 16mh..16mh+16, N cols 32nh..32nh+32
        floatx4 acc1[2];
        acc1[0] = (floatx4){0.f, 0.f, 0.f, 0.f};
        acc1[1] = (floatx4){0.f, 0.f, 0.f, 0.f};

        const unsigned short* w1c = w1e + ((size_t)fc + 32 * nh) * HD;
        #pragma unroll 4
        for (int ks = 0; ks < HD; ks += 32) {
            bf16x8 a  = *(const bf16x8*)&xs[(16 * mh + lr) * XS_LD + ks + lk];
            bf16x8 b0 = *(const bf16x8*)(w1c + (size_t)lr * HD + ks + lk);
            bf16x8 b1f = *(const bf16x8*)(w1c + (size_t)(16 + lr) * HD + ks + lk);
            acc1[0] = __builtin_amdgcn_mfma_f32_16x16x32_bf16(a, b0, acc1[0], 0, 0, 0);
            acc1[1] = __builtin_amdgcn_mfma_f32_16x16x32_bf16(a, b1f, acc1[1], 0, 0, 0);
        }

        __syncthreads();   // previous GEMM2 done reading hs
        #pragma unroll
        for (int t = 0; t < 2; t++) {
            float b1v = b1[e * DFF + z * ZSLICE + fc + 32 * nh + 16 * t + lr];
            #pragma unroll
            for (int r = 0; r < 4; r++) {
                float v = acc1[t][r] + b1v;
                float g = 0.5f * v * (1.f + erff(v * 0.70710678118654752f));  // exact gelu
                hs[(16 * mh + crow + r) * HS_LD + 32 * nh + 16 * t + lr] = f2bf(g);
            }
        }
        __syncthreads();   // hs ready

        // ---- GEMM2: out(32x512) += h-chunk(32x64) @ W2slice[fc:fc+64, :]
        const unsigned short* w2c = w2e + fc;
        #pragma unroll
        for (int ks = 0; ks < FK; ks += 32) {
            bf16x8 af0 = *(const bf16x8*)&hs[lr * HS_LD + ks + lk];
            bf16x8 af1 = *(const bf16x8*)&hs[(16 + lr) * HS_LD + ks + lk];
            #pragma unroll 4
            for (int j = 0; j < 8; j++) {
                bf16x8 b = *(const bf16x8*)(w2c + (size_t)(128 * w + 16 * j + lr) * DFF + ks + lk);
                acc2[0][j] = __builtin_amdgcn_mfma_f32_16x16x32_bf16(af0, b, acc2[0][j], 0, 0, 0);
                acc2[1][j] = __builtin_amdgcn_mfma_f32_16x16x32_bf16(af1, b, acc2[1][j], 0, 0, 0);
            }
        }
    }

    // ---- epilogue: (+b2 once, by z==0), scale by gate weight, atomic add
    #pragma unroll
    for (int j = 0; j < 8; j++) {
        int n = 128 * w + 16 * j + lr;
        float b2v = (z == 0) ? b2[e * HD + n] : 0.f;
        #pragma unroll
        for (int i = 0; i < 2; i++) {
            #pragma unroll
            for (int r = 0; r < 4; r++) {
                int m = 16 * i + crow + r;
                float val = (acc2[i][j][r] + b2v) * wgt_s[m];
                atomicAdd(&out[(size_t)tok_s[m] * HD + n], val);
            }
        }
    }
}

extern "C" void kernel_launch(void* const* d_in, const int* in_sizes, int n_in,
                              void* d_out, int out_size, void* d_ws, size_t ws_size,
                              hipStream_t stream)
{
    const float* x  = (const float*)d_in[0];
    const float* gW = (const float*)d_in[1];
    const float* gb = (const float*)d_in[2];
    const float* W1 = (const float*)d_in[3];
    const float* b1 = (const float*)d_in[4];
    const float* W2 = (const float*)d_in[5];
    const float* b2 = (const float*)d_in[6];
    float* out = (float*)d_out;

    // workspace layout
    int*   seg_count = (int*)d_ws;                                   // 8 ints @0
    float* probs_sum = (float*)((char*)d_ws + 32);                   // 8 floats
    int*   seg_token = (int*)((char*)d_ws + 256);                    // [NE][TOK]
    float* seg_w     = (float*)((char*)d_ws + 256 + (size_t)NE * TOK * 4);
    unsigned short* xb  = (unsigned short*)((char*)d_ws + (1u << 20));    // 8 MB
    unsigned short* W1t = (unsigned short*)((char*)d_ws + (16u << 20));   // 16 MB
    unsigned short* W2t = (unsigned short*)((char*)d_ws + (32u << 20));   // 16 MB

    hipMemsetAsync(d_ws, 0, 64, stream);
    hipMemsetAsync(d_out, 0, (size_t)TOK * HD * sizeof(float), stream);

    gate_kernel<<<TOK / 256, 256, 0, stream>>>(x, gW, gb, seg_count, probs_sum,
                                               seg_token, seg_w, xb);
    finalize_kernel<<<1, 64, 0, stream>>>(seg_count, probs_sum, out + (size_t)TOK * HD);

    // W1 [E][HD][DFF] -> W1t [E][DFF][HD]
    transpose_bf16_kernel<<<dim3(DFF / 64, HD / 64, NE), 256, 0, stream>>>(W1, W1t, HD, DFF);
    // W2 [E][DFF][HD] -> W2t [E][HD][DFF]
    transpose_bf16_kernel<<<dim3(HD / 64, DFF / 64, NE), 256, 0, stream>>>(W2, W2t, DFF, HD);

    ffn_mfma_kernel<<<dim3(TOK / BMT, ZN, NE), 256, 0, stream>>>(
        xb, W1t, b1, W2t, b2, seg_count, seg_token, seg_w, out);
}

// Round 4
// 1159.480 us; speedup vs baseline: 1.1924x; 1.1924x over previous
//
#include <hip/hip_runtime.h>
#include <math.h>

#define TOK 8192   // B*S tokens
#define HD  512    // hidden
#define NE  8      // experts
#define DFF 2048   // ffn dim

// ---------- bf16 helpers ----------
typedef __attribute__((ext_vector_type(8))) short bf16x8;
typedef __attribute__((ext_vector_type(4))) float floatx4;

__device__ inline unsigned short f2bf(float f) {
    union { float f; unsigned u; } v; v.f = f;
    unsigned r = v.u + 0x7FFFu + ((v.u >> 16) & 1u);   // round-nearest-even
    return (unsigned short)(r >> 16);
}

// ---------------- gating (fp32, exact) + fused x->bf16 conversion ----------------
__global__ __launch_bounds__(256) void gate_kernel(
    const float* __restrict__ x, const float* __restrict__ gW, const float* __restrict__ gb,
    int* __restrict__ seg_count, float* __restrict__ probs_sum,
    int* __restrict__ seg_token, float* __restrict__ seg_w,
    unsigned short* __restrict__ xb)
{
    __shared__ float sW[HD * NE];
    __shared__ float psum[NE];
    __shared__ int   lcount[NE];
    __shared__ int   lbase[NE];

    int tid = threadIdx.x;
    for (int i = tid; i < HD * NE; i += 256) sW[i] = gW[i];
    if (tid < NE) { psum[tid] = 0.f; lcount[tid] = 0; }
    __syncthreads();

    int t = blockIdx.x * 256 + tid;
    float logit[NE];
    #pragma unroll
    for (int e = 0; e < NE; e++) logit[e] = gb[e];

    const float4* xr4 = reinterpret_cast<const float4*>(x + (size_t)t * HD);
    ushort4* xbw = reinterpret_cast<ushort4*>(xb + (size_t)t * HD);
    for (int j4 = 0; j4 < HD / 4; j4++) {
        float4 xv = xr4[j4];
        int j = j4 * 4;
        ushort4 o; o.x = f2bf(xv.x); o.y = f2bf(xv.y); o.z = f2bf(xv.z); o.w = f2bf(xv.w);
        xbw[j4] = o;
        #pragma unroll
        for (int e = 0; e < NE; e++) {
            logit[e] += xv.x * sW[(j + 0) * NE + e] + xv.y * sW[(j + 1) * NE + e]
                      + xv.z * sW[(j + 2) * NE + e] + xv.w * sW[(j + 3) * NE + e];
        }
    }

    float mx = logit[0];
    #pragma unroll
    for (int e = 1; e < NE; e++) mx = fmaxf(mx, logit[e]);
    float pe[NE]; float s = 0.f;
    #pragma unroll
    for (int e = 0; e < NE; e++) { pe[e] = expf(logit[e] - mx); s += pe[e]; }
    float inv = 1.f / s;
    int l = tid & 63;
    #pragma unroll
    for (int e = 0; e < NE; e++) {          // wave-shuffle reduce, 1 LDS atomic per wave per e
        float v = pe[e] * inv;
        for (int off = 32; off; off >>= 1) v += __shfl_down(v, off);
        if (l == 0) atomicAdd(&psum[e], v);
    }

    // top-2, lowest-index tie break (matches jax.lax.top_k)
    int i0 = 0; float v0 = logit[0];
    #pragma unroll
    for (int e = 1; e < NE; e++) if (logit[e] > v0) { v0 = logit[e]; i0 = e; }
    int i1 = -1; float v1 = -3.4e38f;
    #pragma unroll
    for (int e = 0; e < NE; e++) if (e != i0 && logit[e] > v1) { v1 = logit[e]; i1 = e; }
    float e1 = expf(v1 - v0);
    float w0 = 1.f / (1.f + e1);
    float w1 = e1 / (1.f + e1);

    int r0 = atomicAdd(&lcount[i0], 1);
    int r1 = atomicAdd(&lcount[i1], 1);
    __syncthreads();
    if (tid < NE) lbase[tid] = atomicAdd(&seg_count[tid], lcount[tid]);
    __syncthreads();
    int p0 = lbase[i0] + r0;
    seg_token[i0 * TOK + p0] = t; seg_w[i0 * TOK + p0] = w0;
    int p1 = lbase[i1] + r1;
    seg_token[i1 * TOK + p1] = t; seg_w[i1 * TOK + p1] = w1;

    __syncthreads();
    if (tid < NE) atomicAdd(&probs_sum[tid], psum[tid]);
}

// ---------------- l_aux + counts ----------------
__global__ void finalize_kernel(const int* __restrict__ seg_count,
                                const float* __restrict__ probs_sum,
                                float* __restrict__ out_tail)
{
    int tid = threadIdx.x;
    __shared__ float p2[NE];
    if (tid < NE) {
        float p = probs_sum[tid] * (1.f / (float)TOK);
        p2[tid] = p * p;
        out_tail[1 + tid] = (float)seg_count[tid];
    }
    __syncthreads();
    if (tid == 0) {
        float ssum = 0.f;
        #pragma unroll
        for (int e = 0; e < NE; e++) ssum += p2[e];
        out_tail[0] = ssum * (float)NE;
    }
}

// ---------------- weight transpose: [E][R][C] fp32 -> [E][C][R] bf16 ----------------
__global__ __launch_bounds__(256) void transpose_bf16_kernel(const float* __restrict__ in,
                                                             unsigned short* __restrict__ out,
                                                             int R, int C)
{
    __shared__ float tile[64][65];
    int e = blockIdx.z;
    const float* src = in + (size_t)e * R * C;
    unsigned short* dst = out + (size_t)e * R * C;
    int c0 = blockIdx.x * 64, r0 = blockIdx.y * 64;
    int lc = threadIdx.x & 63, lrw = threadIdx.x >> 6;   // 4 row-groups
    #pragma unroll
    for (int rr = lrw; rr < 64; rr += 4)
        tile[rr][lc] = src[(size_t)(r0 + rr) * C + c0 + lc];
    __syncthreads();
    #pragma unroll
    for (int cc = lrw; cc < 64; cc += 4)
        dst[(size_t)(c0 + cc) * R + r0 + lc] = f2bf(tile[lc][cc]);
}

// ---------------- fused MFMA expert FFN ----------------
// Flat 1-D grid; e = bid & 7 so (with round-robin block->XCD dispatch) each XCD
// mostly runs ONE expert -> its 4 MB bf16 weights fit that XCD's 4 MB L2.
// Block = 32 tokens x one expert x one DFF z-slice. 4 waves.
#define BMT 32     // tokens per block
#define FK  64     // dff chunk
#define ZN  2      // DFF split factor
#define ZSLICE (DFF / ZN)
#define XS_LD 520  // xs leading dim (bf16): 1040 B -> 2-way bank alias (free)
#define HS_LD 72   // hs leading dim: 144 B -> 2-way bank alias (free)

__global__ __launch_bounds__(256, 3) void ffn_mfma_kernel(
    const unsigned short* __restrict__ xb,
    const unsigned short* __restrict__ W1t,   // [E][DFF][HD] bf16 (n-major)
    const float* __restrict__ b1,
    const unsigned short* __restrict__ W2t,   // [E][HD][DFF] bf16 (n-major)
    const float* __restrict__ b2,
    const int* __restrict__ seg_count, const int* __restrict__ seg_token,
    const float* __restrict__ seg_w, float* __restrict__ out)
{
    int bid = blockIdx.x;
    int e = bid & 7;            // XCD-affinity: same expert -> same XCD (heuristic)
    int rest = bid >> 3;
    int z = rest & (ZN - 1);
    int g = rest >> 1;
    int cnt = seg_count[e];
    int n0 = g * BMT;
    if (n0 >= cnt) return;
    int rows = min(BMT, cnt - n0);

    __shared__ unsigned short xs[BMT * XS_LD];   // 33280 B
    __shared__ unsigned short hs[BMT * HS_LD];   //  4608 B
    __shared__ int   tok_s[BMT];
    __shared__ float wgt_s[BMT];

    int tid = threadIdx.x;
    if (tid < BMT) {
        int idx = (tid < rows) ? (n0 + tid) : n0;            // pad rows duplicate row 0
        tok_s[tid] = seg_token[e * TOK + idx];
        wgt_s[tid] = (tid < rows) ? seg_w[e * TOK + idx] : 0.f;
    }
    __syncthreads();

    // stage x rows (bf16): 8 threads per row, 128 B each
    {
        int r = tid >> 3, q = tid & 7;
        const uint4* src = (const uint4*)(xb + (size_t)tok_s[r] * HD) + q * 8;
        uint4* dst = (uint4*)&xs[(size_t)r * XS_LD + q * 64];
        #pragma unroll
        for (int i = 0; i < 8; i++) dst[i] = src[i];
    }
    __syncthreads();

    int w  = tid >> 6;          // wave id 0..3
    int l  = tid & 63;
    int lr = l & 15;
    int lk = (l >> 4) * 8;
    int crow = (l >> 4) * 4;
    int mh = w & 1;             // GEMM1 M-half
    int nh = w >> 1;            // GEMM1 N-half

    const unsigned short* w1e = W1t + ((size_t)e * DFF + (size_t)z * ZSLICE) * HD;
    const unsigned short* w2e = W2t + (size_t)e * HD * DFF + (size_t)z * ZSLICE;

    floatx4 acc2[2][8];         // 32 M x 128 N per wave
    #pragma unroll
    for (int i = 0; i < 2; i++)
        #pragma unroll
        for (int j = 0; j < 8; j++)
            acc2[i][j] = (floatx4){0.f, 0.f, 0.f, 0.f};

    for (int fc = 0; fc < ZSLICE; fc += FK) {
        // ---- GEMM1: h-chunk(32x64) = xs(32x512) @ W1slice[:, fc:fc+64]
        // wave(mh,nh): M rows 16mh..16mh+16, N cols 32nh..32nh+32
        floatx4 acc1[2];
        acc1[0] = (floatx4){0.f, 0.f, 0.f, 0.f};
        acc1[1] = (floatx4){0.f, 0.f, 0.f, 0.f};

        const unsigned short* w1c = w1e + ((size_t)fc + 32 * nh) * HD;
        #pragma unroll 4
        for (int ks = 0; ks < HD; ks += 32) {
            bf16x8 a  = *(const bf16x8*)&xs[(16 * mh + lr) * XS_LD + ks + lk];
            bf16x8 b0 = *(const bf16x8*)(w1c + (size_t)lr * HD + ks + lk);
            bf16x8 b1f = *(const bf16x8*)(w1c + (size_t)(16 + lr) * HD + ks + lk);
            acc1[0] = __builtin_amdgcn_mfma_f32_16x16x32_bf16(a, b0, acc1[0], 0, 0, 0);
            acc1[1] = __builtin_amdgcn_mfma_f32_16x16x32_bf16(a, b1f, acc1[1], 0, 0, 0);
        }

        __syncthreads();   // previous GEMM2 done reading hs
        #pragma unroll
        for (int t = 0; t < 2; t++) {
            float b1v = b1[e * DFF + z * ZSLICE + fc + 32 * nh + 16 * t + lr];
            #pragma unroll
            for (int r = 0; r < 4; r++) {
                float v = acc1[t][r] + b1v;
                float g = 0.5f * v * (1.f + erff(v * 0.70710678118654752f));  // exact gelu
                hs[(16 * mh + crow + r) * HS_LD + 32 * nh + 16 * t + lr] = f2bf(g);
            }
        }
        __syncthreads();   // hs ready

        // ---- GEMM2: out(32x512) += h-chunk(32x64) @ W2slice[fc:fc+64, :]
        const unsigned short* w2c = w2e + fc;
        #pragma unroll
        for (int ks = 0; ks < FK; ks += 32) {
            bf16x8 af0 = *(const bf16x8*)&hs[lr * HS_LD + ks + lk];
            bf16x8 af1 = *(const bf16x8*)&hs[(16 + lr) * HS_LD + ks + lk];
            #pragma unroll 4
            for (int j = 0; j < 8; j++) {
                bf16x8 b = *(const bf16x8*)(w2c + (size_t)(128 * w + 16 * j + lr) * DFF + ks + lk);
                acc2[0][j] = __builtin_amdgcn_mfma_f32_16x16x32_bf16(af0, b, acc2[0][j], 0, 0, 0);
                acc2[1][j] = __builtin_amdgcn_mfma_f32_16x16x32_bf16(af1, b, acc2[1][j], 0, 0, 0);
            }
        }
    }

    // ---- epilogue: (+b2 once, by z==0), scale by gate weight, atomic add
    #pragma unroll
    for (int j = 0; j < 8; j++) {
        int n = 128 * w + 16 * j + lr;
        float b2v = (z == 0) ? b2[e * HD + n] : 0.f;
        #pragma unroll
        for (int i = 0; i < 2; i++) {
            #pragma unroll
            for (int r = 0; r < 4; r++) {
                int m = 16 * i + crow + r;
                float val = (acc2[i][j][r] + b2v) * wgt_s[m];
                atomicAdd(&out[(size_t)tok_s[m] * HD + n], val);
            }
        }
    }
}

extern "C" void kernel_launch(void* const* d_in, const int* in_sizes, int n_in,
                              void* d_out, int out_size, void* d_ws, size_t ws_size,
                              hipStream_t stream)
{
    const float* x  = (const float*)d_in[0];
    const float* gW = (const float*)d_in[1];
    const float* gb = (const float*)d_in[2];
    const float* W1 = (const float*)d_in[3];
    const float* b1 = (const float*)d_in[4];
    const float* W2 = (const float*)d_in[5];
    const float* b2 = (const float*)d_in[6];
    float* out = (float*)d_out;

    // workspace layout
    int*   seg_count = (int*)d_ws;                                   // 8 ints @0
    float* probs_sum = (float*)((char*)d_ws + 32);                   // 8 floats
    int*   seg_token = (int*)((char*)d_ws + 256);                    // [NE][TOK]
    float* seg_w     = (float*)((char*)d_ws + 256 + (size_t)NE * TOK * 4);
    unsigned short* xb  = (unsigned short*)((char*)d_ws + (1u << 20));    // 8 MB
    unsigned short* W1t = (unsigned short*)((char*)d_ws + (16u << 20));   // 16 MB
    unsigned short* W2t = (unsigned short*)((char*)d_ws + (32u << 20));   // 16 MB

    hipMemsetAsync(d_ws, 0, 64, stream);
    hipMemsetAsync(d_out, 0, (size_t)TOK * HD * sizeof(float), stream);

    gate_kernel<<<TOK / 256, 256, 0, stream>>>(x, gW, gb, seg_count, probs_sum,
                                               seg_token, seg_w, xb);
    finalize_kernel<<<1, 64, 0, stream>>>(seg_count, probs_sum, out + (size_t)TOK * HD);

    // W1 [E][HD][DFF] -> W1t [E][DFF][HD]
    transpose_bf16_kernel<<<dim3(DFF / 64, HD / 64, NE), 256, 0, stream>>>(W1, W1t, HD, DFF);
    // W2 [E][DFF][HD] -> W2t [E][HD][DFF]
    transpose_bf16_kernel<<<dim3(HD / 64, DFF / 64, NE), 256, 0, stream>>>(W2, W2t, DFF, HD);

    ffn_mfma_kernel<<<(TOK / BMT) * ZN * NE, 256, 0, stream>>>(
        xb, W1t, b1, W2t, b2, seg_count, seg_token, seg_w, out);
}